// Round 1
// baseline (1008.571 us; speedup 1.0000x reference)
//
#include <hip/hip_runtime.h>
#include <math.h>

// ---------------------------------------------------------------------------
// SCN layer: h_i = sigmoid(Lhat_i @ (x_i @ W_i)),  Lhat = inv*L*inv (inv = rsqrt(rowsum|L|))
//   x2_out = h2
//   x1_out = graphnorm(h1 + inc2 @ (x2_out @ Wc1), batch_1, gn1)
//   x0_out = graphnorm(h0 + inc1 @ (x1_out @ Wc2), batch,   gn2)
// Round 1: correct fp32 baseline. Tiled fp32 GEMM + deterministic split-K.
// ---------------------------------------------------------------------------

#define EPSV 1e-5f

// ---------------- rowsum -> inv = rsqrt(sum|L[r,:]|) ----------------
__global__ void rowsum_inv_k(const float* __restrict__ L, float* __restrict__ inv, int m) {
  const int r = blockIdx.x;
  const float* row = L + (size_t)r * m;
  const int tid = threadIdx.x;
  float s = 0.f;
  for (int c = tid * 4; c < m; c += 256 * 4) {
    float4 v = *reinterpret_cast<const float4*>(row + c);
    s += fabsf(v.x) + fabsf(v.y) + fabsf(v.z) + fabsf(v.w);
  }
  #pragma unroll
  for (int o = 32; o > 0; o >>= 1) s += __shfl_down(s, o, 64);
  __shared__ float red[4];
  if ((tid & 63) == 0) red[tid >> 6] = s;
  __syncthreads();
  if (tid == 0) {
    float d = red[0] + red[1] + red[2] + red[3];
    inv[r] = (d != 0.f) ? rsqrtf(d) : 0.f;
  }
}

// ---------------- tiled fp32 GEMM: out = A[n x K] @ B[K x 128] ----------------
// MODE 0: partial write to out + blockIdx.y*n*128 (split-K, raw acc)
// MODE 1: final write, acc * scale[row]   (S must be 1)
// MODE 2: final write, raw                (S must be 1)
#define BM 64
#define BN 128
#define BK 32
#define APAD 4

template<int MODE>
__global__ __launch_bounds__(256)
void gemm_k(const float* __restrict__ A, int lda,
            const float* __restrict__ B,
            float* __restrict__ out,
            const float* __restrict__ scale,
            int n, int K, int kchunk)
{
  __shared__ float As[BM][BK + APAD];   // stride 36 floats (float4-aligned)
  __shared__ float Bs[BK][BN];

  const int tid = threadIdx.x;
  const int rowblk = blockIdx.x * BM;
  const int k0 = blockIdx.y * kchunk;
  const int k1 = min(K, k0 + kchunk);

  float acc[8][4];
  #pragma unroll
  for (int i = 0; i < 8; ++i)
    #pragma unroll
    for (int j = 0; j < 4; ++j) acc[i][j] = 0.f;

  const int a_row = tid >> 3;          // 0..31
  const int a_col = (tid & 7) * 4;     // 0,4,...,28
  const int b_row = tid >> 5;          // 0..7
  const int b_col = (tid & 31) * 4;    // 0,4,...,124

  const int row0 = (tid >> 5) * 8;     // 0..56
  const int col0 = (tid & 31) * 4;     // 0..124

  for (int kk = k0; kk < k1; kk += BK) {
    #pragma unroll
    for (int i = 0; i < 2; ++i) {
      int r = a_row + i * 32;
      float4 v = *reinterpret_cast<const float4*>(A + (size_t)(rowblk + r) * lda + kk + a_col);
      *reinterpret_cast<float4*>(&As[r][a_col]) = v;
    }
    #pragma unroll
    for (int i = 0; i < 4; ++i) {
      int r = b_row + i * 8;
      float4 v = *reinterpret_cast<const float4*>(B + (size_t)(kk + r) * BN + b_col);
      *reinterpret_cast<float4*>(&Bs[r][b_col]) = v;
    }
    __syncthreads();
    #pragma unroll
    for (int k = 0; k < BK; ++k) {
      float4 b = *reinterpret_cast<const float4*>(&Bs[k][col0]);
      #pragma unroll
      for (int i = 0; i < 8; ++i) {
        float a = As[row0 + i][k];
        acc[i][0] = fmaf(a, b.x, acc[i][0]);
        acc[i][1] = fmaf(a, b.y, acc[i][1]);
        acc[i][2] = fmaf(a, b.z, acc[i][2]);
        acc[i][3] = fmaf(a, b.w, acc[i][3]);
      }
    }
    __syncthreads();
  }

  float* o = out;
  if (MODE == 0) o += (size_t)blockIdx.y * n * BN;
  #pragma unroll
  for (int i = 0; i < 8; ++i) {
    int r = rowblk + row0 + i;
    float4 v = make_float4(acc[i][0], acc[i][1], acc[i][2], acc[i][3]);
    if (MODE == 1) { float sc = scale[r]; v.x *= sc; v.y *= sc; v.z *= sc; v.w *= sc; }
    *reinterpret_cast<float4*>(o + (size_t)r * BN + col0) = v;
  }
}

// ---------------- split-K reduce + epilogues ----------------
__global__ void reduce_sigmoid_k(const float* __restrict__ part, int S, size_t stride,
                                 const float* __restrict__ inv, float* __restrict__ out, int n) {
  int i = blockIdx.x * blockDim.x + threadIdx.x;   // float4 index
  if (i >= n * 32) return;
  size_t off = (size_t)i * 4;
  float4 s = *reinterpret_cast<const float4*>(part + off);
  for (int sp = 1; sp < S; ++sp) {
    float4 v = *reinterpret_cast<const float4*>(part + (size_t)sp * stride + off);
    s.x += v.x; s.y += v.y; s.z += v.z; s.w += v.w;
  }
  float iv = inv[off >> 7];
  s.x = 1.f / (1.f + expf(-iv * s.x));
  s.y = 1.f / (1.f + expf(-iv * s.y));
  s.z = 1.f / (1.f + expf(-iv * s.z));
  s.w = 1.f / (1.f + expf(-iv * s.w));
  *reinterpret_cast<float4*>(out + off) = s;
}

__global__ void reduce_add_k(const float* __restrict__ part, int S, size_t stride,
                             const float* __restrict__ h, float* __restrict__ z, int n) {
  int i = blockIdx.x * blockDim.x + threadIdx.x;
  if (i >= n * 32) return;
  size_t off = (size_t)i * 4;
  float4 s = *reinterpret_cast<const float4*>(part + off);
  for (int sp = 1; sp < S; ++sp) {
    float4 v = *reinterpret_cast<const float4*>(part + (size_t)sp * stride + off);
    s.x += v.x; s.y += v.y; s.z += v.z; s.w += v.w;
  }
  float4 hv = *reinterpret_cast<const float4*>(h + off);
  s.x += hv.x; s.y += hv.y; s.z += hv.z; s.w += hv.w;
  *reinterpret_cast<float4*>(z + off) = s;
}

// ---------------- graph norm (deterministic, per-segment; batch sorted) ----------------
__device__ inline int lbound(const int* __restrict__ b, int n, int v) {
  int lo = 0, hi = n;
  while (lo < hi) { int mid = (lo + hi) >> 1; if (b[mid] < v) lo = mid + 1; else hi = mid; }
  return lo;
}

__global__ void gn_stats_k(const float* __restrict__ z, const int* __restrict__ batch, int n,
                           const float* __restrict__ mss,
                           float* __restrict__ meanms, float* __restrict__ rstd) {
  const int g = blockIdx.x;     // 64 segments
  const int c = threadIdx.x;    // 128 cols
  __shared__ int lohi[2];
  if (c == 0) { lohi[0] = lbound(batch, n, g); lohi[1] = lbound(batch, n, g + 1); }
  __syncthreads();
  const int lo = lohi[0], hi = lohi[1];
  const float cnt = (float)max(hi - lo, 1);
  float sum = 0.f;
  for (int r = lo; r < hi; ++r) sum += z[(size_t)r * 128 + c];
  const float mn = (sum / cnt) * mss[c];   // mean * mean_scale (what gets subtracted)
  float m2 = 0.f;
  for (int r = lo; r < hi; ++r) { float o = z[(size_t)r * 128 + c] - mn; m2 += o * o; }
  meanms[g * 128 + c] = mn;
  rstd[g * 128 + c] = rsqrtf(m2 / cnt + EPSV);
}

__global__ void gn_apply_k(const float* __restrict__ z, const int* __restrict__ batch,
                           const float* __restrict__ w, const float* __restrict__ b,
                           const float* __restrict__ meanms, const float* __restrict__ rstd,
                           float* __restrict__ out, int n) {
  int i = blockIdx.x * blockDim.x + threadIdx.x;   // float4 index
  if (i >= n * 32) return;
  const int r = i >> 5;
  const int c = (i & 31) * 4;
  const int g = batch[r];
  float4 zv = *reinterpret_cast<const float4*>(z + (size_t)r * 128 + c);
  float4 mm = *reinterpret_cast<const float4*>(meanms + g * 128 + c);
  float4 rs = *reinterpret_cast<const float4*>(rstd + g * 128 + c);
  float4 wv = *reinterpret_cast<const float4*>(w + c);
  float4 bv = *reinterpret_cast<const float4*>(b + c);
  float4 o;
  o.x = wv.x * (zv.x - mm.x) * rs.x + bv.x;
  o.y = wv.y * (zv.y - mm.y) * rs.y + bv.y;
  o.z = wv.z * (zv.z - mm.z) * rs.z + bv.z;
  o.w = wv.w * (zv.w - mm.w) * rs.w + bv.w;
  *reinterpret_cast<float4*>(out + (size_t)r * 128 + c) = o;
}

// ---------------------------------------------------------------------------
extern "C" void kernel_launch(void* const* d_in, const int* in_sizes, int n_in,
                              void* d_out, int out_size, void* d_ws, size_t ws_size,
                              hipStream_t stream) {
  const float* x0   = (const float*)d_in[0];
  const float* x1   = (const float*)d_in[1];
  const float* x2   = (const float*)d_in[2];
  const float* L0   = (const float*)d_in[3];
  const float* L1   = (const float*)d_in[4];
  const float* L2   = (const float*)d_in[5];
  const float* inc1 = (const float*)d_in[6];
  const float* inc2 = (const float*)d_in[7];
  const float* W0   = (const float*)d_in[8];
  const float* W1   = (const float*)d_in[9];
  const float* W2   = (const float*)d_in[10];
  const float* Wc1  = (const float*)d_in[11];
  const float* Wc2  = (const float*)d_in[12];
  const float* g1w  = (const float*)d_in[13];
  const float* g1b  = (const float*)d_in[14];
  const float* g1m  = (const float*)d_in[15];
  const float* g2w  = (const float*)d_in[16];
  const float* g2b  = (const float*)d_in[17];
  const float* g2m  = (const float*)d_in[18];
  const int*   bat0 = (const int*)d_in[19];
  const int*   bat1 = (const int*)d_in[20];

  const int N0 = 4096, N1 = 8192, N2 = 6144;

  float* ws = (float*)d_ws;
  size_t off = 0;
  auto alloc = [&](size_t nf) { float* p = ws + off; off += (nf + 63) & ~(size_t)63; return p; };
  float* inv0   = alloc(N0);
  float* inv1   = alloc(N1);
  float* inv2   = alloc(N2);
  float* t      = alloc((size_t)N1 * 128);
  float* h0     = alloc((size_t)N0 * 128);
  float* h1     = alloc((size_t)N1 * 128);
  float* z      = alloc((size_t)N1 * 128);
  float* meanms = alloc(64 * 128);
  float* rstd   = alloc(64 * 128);
  float* part   = alloc((size_t)6 * N2 * 128);   // max split-K partials (6*6144 rows)

  float* out0 = (float*)d_out;                   // x0_out : 4096 x 128
  float* out1 = out0 + (size_t)N0 * 128;         // x1_out : 8192 x 128
  float* out2 = out1 + (size_t)N1 * 128;         // x2_out : 6144 x 128

  // --- normalization scales ---
  rowsum_inv_k<<<N0, 256, 0, stream>>>(L0, inv0, N0);
  rowsum_inv_k<<<N1, 256, 0, stream>>>(L1, inv1, N1);
  rowsum_inv_k<<<N2, 256, 0, stream>>>(L2, inv2, N2);

  // --- h2 = sigmoid(inv2 * (L2 @ (inv2 * (x2@W2)))) -> out2 directly ---
  gemm_k<1><<<dim3(N2 / BM, 1), 256, 0, stream>>>(x2, 128, W2, t, inv2, N2, 128, 128);
  gemm_k<0><<<dim3(N2 / BM, 6), 256, 0, stream>>>(L2, N2, t, part, nullptr, N2, N2, 1024);
  reduce_sigmoid_k<<<N2 * 32 / 256, 256, 0, stream>>>(part, 6, (size_t)N2 * 128, inv2, out2, N2);

  // --- h1 ---
  gemm_k<1><<<dim3(N1 / BM, 1), 256, 0, stream>>>(x1, 128, W1, t, inv1, N1, 128, 128);
  gemm_k<0><<<dim3(N1 / BM, 4), 256, 0, stream>>>(L1, N1, t, part, nullptr, N1, N1, 2048);
  reduce_sigmoid_k<<<N1 * 32 / 256, 256, 0, stream>>>(part, 4, (size_t)N1 * 128, inv1, h1, N1);

  // --- h0 ---
  gemm_k<1><<<dim3(N0 / BM, 1), 256, 0, stream>>>(x0, 128, W0, t, inv0, N0, 128, 128);
  gemm_k<0><<<dim3(N0 / BM, 8), 256, 0, stream>>>(L0, N0, t, part, nullptr, N0, N0, 512);
  reduce_sigmoid_k<<<N0 * 32 / 256, 256, 0, stream>>>(part, 8, (size_t)N0 * 128, inv0, h0, N0);

  // --- x1_out = graphnorm(h1 + inc2 @ (out2 @ Wc1), batch_1, gn1) ---
  gemm_k<2><<<dim3(N2 / BM, 1), 256, 0, stream>>>(out2, 128, Wc1, t, nullptr, N2, 128, 128);
  gemm_k<0><<<dim3(N1 / BM, 4), 256, 0, stream>>>(inc2, N2, t, part, nullptr, N1, N2, 1536);
  reduce_add_k<<<N1 * 32 / 256, 256, 0, stream>>>(part, 4, (size_t)N1 * 128, h1, z, N1);
  gn_stats_k<<<64, 128, 0, stream>>>(z, bat1, N1, g1m, meanms, rstd);
  gn_apply_k<<<N1 * 32 / 256, 256, 0, stream>>>(z, bat1, g1w, g1b, meanms, rstd, out1, N1);

  // --- x0_out = graphnorm(h0 + inc1 @ (out1 @ Wc2), batch, gn2) ---
  gemm_k<2><<<dim3(N1 / BM, 1), 256, 0, stream>>>(out1, 128, Wc2, t, nullptr, N1, 128, 128);
  gemm_k<0><<<dim3(N0 / BM, 8), 256, 0, stream>>>(inc1, N1, t, part, nullptr, N0, N1, 1024);
  reduce_add_k<<<N0 * 32 / 256, 256, 0, stream>>>(part, 8, (size_t)N0 * 128, h0, z, N0);
  gn_stats_k<<<64, 128, 0, stream>>>(z, bat0, N0, g2m, meanms, rstd);
  gn_apply_k<<<N0 * 32 / 256, 256, 0, stream>>>(z, bat0, g2w, g2b, meanms, rstd, out0, N0);
}

// Round 3
// 743.793 us; speedup vs baseline: 1.3560x; 1.3560x over previous
//
#include <hip/hip_runtime.h>
#include <math.h>

// ---------------------------------------------------------------------------
// SCN layer, round 3: big GEMMs use bf16 MFMA with 3-term hi/lo split
// (A_hi*B_hi + A_hi*B_lo + A_lo*B_hi) -> fp32-level accuracy, memory-bound.
// fp32 operands in HBM; hi/lo extracted in-register during LDS staging.
//   h_i = sigmoid(inv_i * (L_i @ (inv_i * (x_i @ W_i))))
//   x2_out = h2
//   x1_out = graphnorm(h1 + inc2 @ (x2_out @ Wc1), batch_1, gn1)
//   x0_out = graphnorm(h0 + inc1 @ (x1_out @ Wc2), batch,   gn2)
// ---------------------------------------------------------------------------

#define EPSV 1e-5f

typedef unsigned short u16;
typedef short s16x8 __attribute__((ext_vector_type(8)));
typedef u16 u16x8 __attribute__((ext_vector_type(8)));
typedef float f32x4 __attribute__((ext_vector_type(4)));

// LDS plan (bytes): A_hi | A_lo | B_hi | B_lo, each [128 rows][64 bf16] = 16 KB
#define AHI 0
#define ALO 16384
#define BHI 32768
#define BLO 49152

__device__ inline u16 f2bf(float f) {            // RNE fp32 -> bf16 (finite)
  union { float f; unsigned u; } v; v.f = f;
  unsigned r = v.u + 0x7FFF + ((v.u >> 16) & 1);
  return (u16)(r >> 16);
}

// split 8 fp32 -> bf16 hi + bf16 lo (lo = bf16(v - hi))
__device__ inline void split8(f32x4 a, f32x4 b, u16x8& hi, u16x8& lo) {
  float v[8] = {a[0], a[1], a[2], a[3], b[0], b[1], b[2], b[3]};
  #pragma unroll
  for (int j = 0; j < 8; ++j) {
    union { float f; unsigned u; } t; t.f = v[j];
    unsigned r = t.u + 0x7FFF + ((t.u >> 16) & 1);
    unsigned hb = r & 0xFFFF0000u;
    hi[j] = (u16)(hb >> 16);
    union { unsigned u; float f; } hf; hf.u = hb;
    lo[j] = f2bf(v[j] - hf.f);
  }
}

// ---------------- rowsum -> inv = rsqrt(sum|L[r,:]|) ----------------
__global__ void rowsum_inv_k(const float* __restrict__ L, float* __restrict__ inv, int m) {
  const int r = blockIdx.x;
  const float* row = L + (size_t)r * m;
  const int tid = threadIdx.x;
  float s = 0.f;
  for (int c = tid * 4; c < m; c += 256 * 4) {
    float4 v = *reinterpret_cast<const float4*>(row + c);
    s += fabsf(v.x) + fabsf(v.y) + fabsf(v.z) + fabsf(v.w);
  }
  #pragma unroll
  for (int o = 32; o > 0; o >>= 1) s += __shfl_down(s, o, 64);
  __shared__ float red[4];
  if ((tid & 63) == 0) red[tid >> 6] = s;
  __syncthreads();
  if (tid == 0) {
    float d = red[0] + red[1] + red[2] + red[3];
    inv[r] = (d != 0.f) ? rsqrtf(d) : 0.f;
  }
}

// ---------------- small fp32 GEMM: tT[c][r] = (A[Nx128] @ B[128x128])[r][c] * sc[r]
// MODE 1: scale by scale[row]; MODE 2: raw. Output fp32 TRANSPOSED [128][ldo].
template<int MODE>
__global__ __launch_bounds__(256)
void gemm_small_k(const float* __restrict__ A, const float* __restrict__ B,
                  float* __restrict__ outT, int ldo, const float* __restrict__ scale)
{
  __shared__ float As[64][36];
  __shared__ float Bs[32][128];
  const int tid = threadIdx.x;
  const int rowblk = blockIdx.x * 64;

  float acc[8][4];
  #pragma unroll
  for (int i = 0; i < 8; ++i)
    #pragma unroll
    for (int j = 0; j < 4; ++j) acc[i][j] = 0.f;

  const int a_row = tid >> 3, a_col = (tid & 7) * 4;
  const int b_row = tid >> 5, b_col = (tid & 31) * 4;
  const int row0 = (tid >> 5) * 8, col0 = (tid & 31) * 4;

  for (int kk = 0; kk < 128; kk += 32) {
    #pragma unroll
    for (int i = 0; i < 2; ++i) {
      int r = a_row + i * 32;
      *reinterpret_cast<float4*>(&As[r][a_col]) =
          *reinterpret_cast<const float4*>(A + (size_t)(rowblk + r) * 128 + kk + a_col);
    }
    #pragma unroll
    for (int i = 0; i < 4; ++i) {
      int r = b_row + i * 8;
      *reinterpret_cast<float4*>(&Bs[r][b_col]) =
          *reinterpret_cast<const float4*>(B + (size_t)(kk + r) * 128 + b_col);
    }
    __syncthreads();
    #pragma unroll
    for (int k = 0; k < 32; ++k) {
      float4 b = *reinterpret_cast<const float4*>(&Bs[k][col0]);
      #pragma unroll
      for (int i = 0; i < 8; ++i) {
        float a = As[row0 + i][k];
        acc[i][0] = fmaf(a, b.x, acc[i][0]);
        acc[i][1] = fmaf(a, b.y, acc[i][1]);
        acc[i][2] = fmaf(a, b.z, acc[i][2]);
        acc[i][3] = fmaf(a, b.w, acc[i][3]);
      }
    }
    __syncthreads();
  }

  const int rb = rowblk + row0;
  float sc[8];
  #pragma unroll
  for (int i = 0; i < 8; ++i) sc[i] = (MODE == 1) ? scale[rb + i] : 1.0f;
  #pragma unroll
  for (int j = 0; j < 4; ++j) {
    float4 v0 = make_float4(acc[0][j] * sc[0], acc[1][j] * sc[1], acc[2][j] * sc[2], acc[3][j] * sc[3]);
    float4 v1 = make_float4(acc[4][j] * sc[4], acc[5][j] * sc[5], acc[6][j] * sc[6], acc[7][j] * sc[7]);
    *reinterpret_cast<float4*>(outT + (size_t)(col0 + j) * ldo + rb) = v0;
    *reinterpret_cast<float4*>(outT + (size_t)(col0 + j) * ldo + rb + 4) = v1;
  }
}

// ---------------- MFMA GEMM (3-term split): part[split] = A[n x K] @ Bt^T ----------------
// A fp32 [n][K]; Bt fp32 [128][K] (transposed small-GEMM output, L2-resident).
// 128x128 tile, 4 waves (2x2), BK=64, single swizzled LDS buffer + reg prefetch.
__global__ __launch_bounds__(256)
void mfma_gemm_k(const float* __restrict__ A, int lda,
                 const float* __restrict__ Bt, int ldb,
                 float* __restrict__ part,
                 int n, int K, int kchunk)
{
  __shared__ __align__(16) char smem[65536];

  const int tid = threadIdx.x;
  const int rowblk = blockIdx.x * 128;
  const int k0 = blockIdx.y * kchunk;
  const int k1 = min(K, k0 + kchunk);
  const int nsteps = (k1 - k0) >> 6;              // BK = 64

  // staging roles: thread -> (row 0..127, k-half 0/1); 32 fp32 A + 32 fp32 B each
  const int srow = tid >> 1, sh = tid & 1;
  const float* gA = A + (size_t)(rowblk + srow) * lda + k0 + sh * 32;
  const float* gB = Bt + (size_t)srow * ldb + k0 + sh * 32;
  int wsw[4];
  #pragma unroll
  for (int i = 0; i < 4; ++i)
    wsw[i] = (srow << 7) + ((((sh << 2) | i) ^ (srow & 7)) << 4);

  // compute roles
  const int l = tid & 63, w = tid >> 6;
  const int wr = (w >> 1) * 64, wc = (w & 1) * 64;
  const int lrow = l & 15, lks = l >> 4, lsw = l & 7;

  f32x4 acc[4][4];
  #pragma unroll
  for (int mi = 0; mi < 4; ++mi)
    #pragma unroll
    for (int ni = 0; ni < 4; ++ni) acc[mi][ni] = (f32x4){0.f, 0.f, 0.f, 0.f};

  f32x4 ra[8], rbv[8];

#define LOADG(S)                                                            \
  {                                                                         \
    const float* pA = gA + (size_t)(S) * 64;                                \
    const float* pB = gB + (size_t)(S) * 64;                                \
    _Pragma("unroll")                                                       \
    for (int i = 0; i < 8; ++i) {                                           \
      ra[i]  = *reinterpret_cast<const f32x4*>(pA + i * 4);                 \
      rbv[i] = *reinterpret_cast<const f32x4*>(pB + i * 4);                 \
    }                                                                       \
  }

#define STORE_LDS()                                                         \
  {                                                                         \
    _Pragma("unroll")                                                       \
    for (int i = 0; i < 4; ++i) {                                           \
      u16x8 hi, lo;                                                         \
      split8(ra[i * 2], ra[i * 2 + 1], hi, lo);                             \
      *reinterpret_cast<u16x8*>(smem + AHI + wsw[i]) = hi;                  \
      *reinterpret_cast<u16x8*>(smem + ALO + wsw[i]) = lo;                  \
      split8(rbv[i * 2], rbv[i * 2 + 1], hi, lo);                           \
      *reinterpret_cast<u16x8*>(smem + BHI + wsw[i]) = hi;                  \
      *reinterpret_cast<u16x8*>(smem + BLO + wsw[i]) = lo;                  \
    }                                                                       \
  }

  LOADG(0);
  STORE_LDS();
  __syncthreads();

  for (int s = 0; s < nsteps; ++s) {
    if (s + 1 < nsteps) LOADG(s + 1);             // prefetch next tile to regs
    #pragma unroll
    for (int ks = 0; ks < 2; ++ks) {
      const int fo = ((((ks << 2) | lks) ^ lsw) << 4);
      s16x8 bhi[4], blo[4];
      #pragma unroll
      for (int ni = 0; ni < 4; ++ni) {
        const int ro = ((wc + ni * 16 + lrow) << 7) + fo;
        bhi[ni] = *reinterpret_cast<const s16x8*>(smem + BHI + ro);
        blo[ni] = *reinterpret_cast<const s16x8*>(smem + BLO + ro);
      }
      #pragma unroll
      for (int mi = 0; mi < 4; ++mi) {
        const int ro = ((wr + mi * 16 + lrow) << 7) + fo;
        s16x8 ahi = *reinterpret_cast<const s16x8*>(smem + AHI + ro);
        s16x8 alo = *reinterpret_cast<const s16x8*>(smem + ALO + ro);
        #pragma unroll
        for (int ni = 0; ni < 4; ++ni) {
          acc[mi][ni] = __builtin_amdgcn_mfma_f32_16x16x32_bf16(alo, bhi[ni], acc[mi][ni], 0, 0, 0);
          acc[mi][ni] = __builtin_amdgcn_mfma_f32_16x16x32_bf16(ahi, blo[ni], acc[mi][ni], 0, 0, 0);
          acc[mi][ni] = __builtin_amdgcn_mfma_f32_16x16x32_bf16(ahi, bhi[ni], acc[mi][ni], 0, 0, 0);
        }
      }
    }
    __syncthreads();
    if (s + 1 < nsteps) {
      STORE_LDS();
    }
    __syncthreads();
  }

  // epilogue: partial store (C/D: col = lane&15, row = (lane>>4)*4 + reg)
  float* o = part + (size_t)blockIdx.y * n * 128;
  #pragma unroll
  for (int mi = 0; mi < 4; ++mi)
    #pragma unroll
    for (int ni = 0; ni < 4; ++ni) {
      const int gr = rowblk + wr + mi * 16 + lks * 4;
      const int gc = wc + ni * 16 + lrow;
      f32x4 v = acc[mi][ni];
      #pragma unroll
      for (int q = 0; q < 4; ++q) o[(size_t)(gr + q) * 128 + gc] = v[q];
    }
#undef LOADG
#undef STORE_LDS
}

// ---------------- split-K reduce + epilogues ----------------
__global__ void reduce_sigmoid_k(const float* __restrict__ part, int S, size_t stride,
                                 const float* __restrict__ inv, float* __restrict__ out, int n) {
  int i = blockIdx.x * blockDim.x + threadIdx.x;
  if (i >= n * 32) return;
  size_t off = (size_t)i * 4;
  float4 s = *reinterpret_cast<const float4*>(part + off);
  for (int sp = 1; sp < S; ++sp) {
    float4 v = *reinterpret_cast<const float4*>(part + (size_t)sp * stride + off);
    s.x += v.x; s.y += v.y; s.z += v.z; s.w += v.w;
  }
  float iv = inv[off >> 7];
  s.x = 1.f / (1.f + expf(-iv * s.x));
  s.y = 1.f / (1.f + expf(-iv * s.y));
  s.z = 1.f / (1.f + expf(-iv * s.z));
  s.w = 1.f / (1.f + expf(-iv * s.w));
  *reinterpret_cast<float4*>(out + off) = s;
}

__global__ void reduce_add_k(const float* __restrict__ part, int S, size_t stride,
                             const float* __restrict__ h, float* __restrict__ z, int n) {
  int i = blockIdx.x * blockDim.x + threadIdx.x;
  if (i >= n * 32) return;
  size_t off = (size_t)i * 4;
  float4 s = *reinterpret_cast<const float4*>(part + off);
  for (int sp = 1; sp < S; ++sp) {
    float4 v = *reinterpret_cast<const float4*>(part + (size_t)sp * stride + off);
    s.x += v.x; s.y += v.y; s.z += v.z; s.w += v.w;
  }
  float4 hv = *reinterpret_cast<const float4*>(h + off);
  s.x += hv.x; s.y += hv.y; s.z += hv.z; s.w += hv.w;
  *reinterpret_cast<float4*>(z + off) = s;
}

// ---------------- graph norm ----------------
__device__ inline int lbound(const int* __restrict__ b, int n, int v) {
  int lo = 0, hi = n;
  while (lo < hi) { int mid = (lo + hi) >> 1; if (b[mid] < v) lo = mid + 1; else hi = mid; }
  return lo;
}

__global__ void gn_stats_k(const float* __restrict__ z, const int* __restrict__ batch, int n,
                           const float* __restrict__ mss,
                           float* __restrict__ meanms, float* __restrict__ rstd) {
  const int g = blockIdx.x;
  const int c = threadIdx.x;
  __shared__ int lohi[2];
  if (c == 0) { lohi[0] = lbound(batch, n, g); lohi[1] = lbound(batch, n, g + 1); }
  __syncthreads();
  const int lo = lohi[0], hi = lohi[1];
  const float cnt = (float)max(hi - lo, 1);
  float sum = 0.f;
  for (int r = lo; r < hi; ++r) sum += z[(size_t)r * 128 + c];
  const float mn = (sum / cnt) * mss[c];
  float m2 = 0.f;
  for (int r = lo; r < hi; ++r) { float o = z[(size_t)r * 128 + c] - mn; m2 += o * o; }
  meanms[g * 128 + c] = mn;
  rstd[g * 128 + c] = rsqrtf(m2 / cnt + EPSV);
}

__global__ void gn_apply_k(const float* __restrict__ z, const int* __restrict__ batch,
                           const float* __restrict__ w, const float* __restrict__ b,
                           const float* __restrict__ meanms, const float* __restrict__ rstd,
                           float* __restrict__ out, int n) {
  int i = blockIdx.x * blockDim.x + threadIdx.x;
  if (i >= n * 32) return;
  const int r = i >> 5;
  const int c = (i & 31) * 4;
  const int g = batch[r];
  float4 zv = *reinterpret_cast<const float4*>(z + (size_t)r * 128 + c);
  float4 mm = *reinterpret_cast<const float4*>(meanms + g * 128 + c);
  float4 rs = *reinterpret_cast<const float4*>(rstd + g * 128 + c);
  float4 wv = *reinterpret_cast<const float4*>(w + c);
  float4 bv = *reinterpret_cast<const float4*>(b + c);
  float4 o;
  o.x = wv.x * (zv.x - mm.x) * rs.x + bv.x;
  o.y = wv.y * (zv.y - mm.y) * rs.y + bv.y;
  o.z = wv.z * (zv.z - mm.z) * rs.z + bv.z;
  o.w = wv.w * (zv.w - mm.w) * rs.w + bv.w;
  *reinterpret_cast<float4*>(out + (size_t)r * 128 + c) = o;
}

// ---------------------------------------------------------------------------
extern "C" void kernel_launch(void* const* d_in, const int* in_sizes, int n_in,
                              void* d_out, int out_size, void* d_ws, size_t ws_size,
                              hipStream_t stream) {
  const float* x0   = (const float*)d_in[0];
  const float* x1   = (const float*)d_in[1];
  const float* x2   = (const float*)d_in[2];
  const float* L0   = (const float*)d_in[3];
  const float* L1   = (const float*)d_in[4];
  const float* L2   = (const float*)d_in[5];
  const float* inc1 = (const float*)d_in[6];
  const float* inc2 = (const float*)d_in[7];
  const float* W0   = (const float*)d_in[8];
  const float* W1   = (const float*)d_in[9];
  const float* W2   = (const float*)d_in[10];
  const float* Wc1  = (const float*)d_in[11];
  const float* Wc2  = (const float*)d_in[12];
  const float* g1w  = (const float*)d_in[13];
  const float* g1b  = (const float*)d_in[14];
  const float* g1m  = (const float*)d_in[15];
  const float* g2w  = (const float*)d_in[16];
  const float* g2b  = (const float*)d_in[17];
  const float* g2m  = (const float*)d_in[18];
  const int*   bat0 = (const int*)d_in[19];
  const int*   bat1 = (const int*)d_in[20];

  const int N0 = 4096, N1 = 8192, N2 = 6144;

  float* ws = (float*)d_ws;
  size_t off = 0;
  auto alloc = [&](size_t nf) { float* p = ws + off; off += (nf + 63) & ~(size_t)63; return p; };
  float* inv0   = alloc(N0);
  float* inv1   = alloc(N1);
  float* inv2   = alloc(N2);
  float* tT     = alloc((size_t)N1 * 128);         // fp32 transposed t, [128][<=N1]
  float* h0     = alloc((size_t)N0 * 128);
  float* h1     = alloc((size_t)N1 * 128);
  float* z      = alloc((size_t)N1 * 128);
  float* meanms = alloc(64 * 128);
  float* rstd   = alloc(64 * 128);
  float* part   = alloc((size_t)32768 * 128);      // split-K partials (max S*n = 32768 rows)

  float* out0 = (float*)d_out;
  float* out1 = out0 + (size_t)N0 * 128;
  float* out2 = out1 + (size_t)N1 * 128;

  rowsum_inv_k<<<N0, 256, 0, stream>>>(L0, inv0, N0);
  rowsum_inv_k<<<N1, 256, 0, stream>>>(L1, inv1, N1);
  rowsum_inv_k<<<N2, 256, 0, stream>>>(L2, inv2, N2);

  // --- h2 -> out2 ---  (48 rowblocks x S=5 = 240 blocks)
  gemm_small_k<1><<<N2 / 64, 256, 0, stream>>>(x2, W2, tT, N2, inv2);
  mfma_gemm_k<<<dim3(N2 / 128, 5), 256, 0, stream>>>(L2, N2, tT, N2, part, N2, N2, 1280);
  reduce_sigmoid_k<<<N2 * 32 / 256, 256, 0, stream>>>(part, 5, (size_t)N2 * 128, inv2, out2, N2);

  // --- h1 ---  (64 x 4 = 256 blocks)
  gemm_small_k<1><<<N1 / 64, 256, 0, stream>>>(x1, W1, tT, N1, inv1);
  mfma_gemm_k<<<dim3(N1 / 128, 4), 256, 0, stream>>>(L1, N1, tT, N1, part, N1, N1, 2048);
  reduce_sigmoid_k<<<N1 * 32 / 256, 256, 0, stream>>>(part, 4, (size_t)N1 * 128, inv1, h1, N1);

  // --- h0 ---  (32 x 8 = 256 blocks)
  gemm_small_k<1><<<N0 / 64, 256, 0, stream>>>(x0, W0, tT, N0, inv0);
  mfma_gemm_k<<<dim3(N0 / 128, 8), 256, 0, stream>>>(L0, N0, tT, N0, part, N0, N0, 512);
  reduce_sigmoid_k<<<N0 * 32 / 256, 256, 0, stream>>>(part, 8, (size_t)N0 * 128, inv0, h0, N0);

  // --- x1_out ---  (64 x 4 = 256 blocks, K = N2)
  gemm_small_k<2><<<N2 / 64, 256, 0, stream>>>(out2, Wc1, tT, N2, nullptr);
  mfma_gemm_k<<<dim3(N1 / 128, 4), 256, 0, stream>>>(inc2, N2, tT, N2, part, N1, N2, 1536);
  reduce_add_k<<<N1 * 32 / 256, 256, 0, stream>>>(part, 4, (size_t)N1 * 128, h1, z, N1);
  gn_stats_k<<<64, 128, 0, stream>>>(z, bat1, N1, g1m, meanms, rstd);
  gn_apply_k<<<N1 * 32 / 256, 256, 0, stream>>>(z, bat1, g1w, g1b, meanms, rstd, out1, N1);

  // --- x0_out ---  (32 x 8 = 256 blocks, K = N1)
  gemm_small_k<2><<<N1 / 64, 256, 0, stream>>>(out1, Wc2, tT, N1, nullptr);
  mfma_gemm_k<<<dim3(N0 / 128, 8), 256, 0, stream>>>(inc1, N1, tT, N1, part, N0, N1, 1024);
  reduce_add_k<<<N0 * 32 / 256, 256, 0, stream>>>(part, 8, (size_t)N0 * 128, h0, z, N0);
  gn_stats_k<<<64, 128, 0, stream>>>(z, bat0, N0, g2m, meanms, rstd);
  gn_apply_k<<<N0 * 32 / 256, 256, 0, stream>>>(z, bat0, g2w, g2b, meanms, rstd, out0, N0);
}

// Round 4
// 511.919 us; speedup vs baseline: 1.9702x; 1.4529x over previous
//
#include <hip/hip_runtime.h>
#include <math.h>

// ---------------------------------------------------------------------------
// SCN layer, round 4: big GEMMs -> single-term fp16 MFMA (16x16x32_f16).
// fp32 A read coalesced (1KB/wave-instr), in-register RNE cvt to fp16 during
// swizzled LDS staging; B pre-converted to fp16 by the small GEMM (L2-resident).
// Split-K grid ~384 blocks/GEMM, 32KB LDS, 2-3 blocks/CU.
// ---------------------------------------------------------------------------

#define EPSV 1e-5f

typedef unsigned short u16;
typedef u16 u16x8 __attribute__((ext_vector_type(8)));
typedef float f32x4 __attribute__((ext_vector_type(4)));
typedef _Float16 f16x4 __attribute__((ext_vector_type(4)));
typedef _Float16 f16x8 __attribute__((ext_vector_type(8)));

#define LDS_A 0        // [128 rows][64 k] fp16 = 16KB, XOR-swizzled 16B slots
#define LDS_B 16384    // same layout for B (rows = N-dim of tile)

// ---------------- rowsum -> inv = rsqrt(sum|L[r,:]|) ----------------
__global__ void rowsum_inv_k(const float* __restrict__ L, float* __restrict__ inv, int m) {
  const int r = blockIdx.x;
  const float* row = L + (size_t)r * m;
  const int tid = threadIdx.x;
  float s = 0.f;
  for (int c = tid * 4; c < m; c += 256 * 4) {
    float4 v = *reinterpret_cast<const float4*>(row + c);
    s += fabsf(v.x) + fabsf(v.y) + fabsf(v.z) + fabsf(v.w);
  }
  #pragma unroll
  for (int o = 32; o > 0; o >>= 1) s += __shfl_down(s, o, 64);
  __shared__ float red[4];
  if ((tid & 63) == 0) red[tid >> 6] = s;
  __syncthreads();
  if (tid == 0) {
    float d = red[0] + red[1] + red[2] + red[3];
    inv[r] = (d != 0.f) ? rsqrtf(d) : 0.f;
  }
}

// ---------------- small fp32 GEMM: tT[c][r] = fp16( (A[Nx128]@B[128x128])[r][c] * sc[r] )
// MODE 1: scale by scale[row]; MODE 2: raw. Output fp16 TRANSPOSED [128][ldo].
template<int MODE>
__global__ __launch_bounds__(256)
void gemm_small_k(const float* __restrict__ A, const float* __restrict__ B,
                  u16* __restrict__ outT, int ldo, const float* __restrict__ scale)
{
  __shared__ float As[64][36];
  __shared__ float Bs[32][128];
  const int tid = threadIdx.x;
  const int rowblk = blockIdx.x * 64;

  float acc[8][4];
  #pragma unroll
  for (int i = 0; i < 8; ++i)
    #pragma unroll
    for (int j = 0; j < 4; ++j) acc[i][j] = 0.f;

  const int a_row = tid >> 3, a_col = (tid & 7) * 4;
  const int b_row = tid >> 5, b_col = (tid & 31) * 4;
  const int row0 = (tid >> 5) * 8, col0 = (tid & 31) * 4;

  for (int kk = 0; kk < 128; kk += 32) {
    #pragma unroll
    for (int i = 0; i < 2; ++i) {
      int r = a_row + i * 32;
      *reinterpret_cast<float4*>(&As[r][a_col]) =
          *reinterpret_cast<const float4*>(A + (size_t)(rowblk + r) * 128 + kk + a_col);
    }
    #pragma unroll
    for (int i = 0; i < 4; ++i) {
      int r = b_row + i * 8;
      *reinterpret_cast<float4*>(&Bs[r][b_col]) =
          *reinterpret_cast<const float4*>(B + (size_t)(kk + r) * 128 + b_col);
    }
    __syncthreads();
    #pragma unroll
    for (int k = 0; k < 32; ++k) {
      float4 b = *reinterpret_cast<const float4*>(&Bs[k][col0]);
      #pragma unroll
      for (int i = 0; i < 8; ++i) {
        float a = As[row0 + i][k];
        acc[i][0] = fmaf(a, b.x, acc[i][0]);
        acc[i][1] = fmaf(a, b.y, acc[i][1]);
        acc[i][2] = fmaf(a, b.z, acc[i][2]);
        acc[i][3] = fmaf(a, b.w, acc[i][3]);
      }
    }
    __syncthreads();
  }

  const int rb = rowblk + row0;
  float sc[8];
  #pragma unroll
  for (int i = 0; i < 8; ++i) sc[i] = (MODE == 1) ? scale[rb + i] : 1.0f;
  #pragma unroll
  for (int j = 0; j < 4; ++j) {
    u16x8 p;
    #pragma unroll
    for (int i = 0; i < 8; ++i) {
      union { _Float16 h; u16 u; } c;
      c.h = (_Float16)(acc[i][j] * sc[i]);     // v_cvt_f16_f32 (RNE)
      p[i] = c.u;
    }
    *reinterpret_cast<u16x8*>(outT + (size_t)(col0 + j) * ldo + rb) = p;
  }
}

// ---------------- MFMA GEMM (fp16): part[split] = A[n x K](fp32) @ Bt^T ----------------
// A fp32 [n][K]; Bt fp16 [128][K]. 128x128 tile, 4 waves (2x2), BK=64,
// single swizzled LDS buffer + register prefetch, coalesced staging.
__global__ __launch_bounds__(256, 3)
void mfma_gemm_k(const float* __restrict__ A, int lda,
                 const u16* __restrict__ Bt, int ldb,
                 float* __restrict__ part,
                 int n, int K, int kchunk)
{
  __shared__ __align__(16) char smem[32768];

  const int tid = threadIdx.x;
  const int rowblk = blockIdx.x * 128;
  const int k0 = blockIdx.y * kchunk;
  const int k1 = min(K, k0 + kchunk);
  const int nsteps = (k1 - k0) >> 6;             // may be <= 0 (tail split)

  // ---- staging maps (coalesced: each wave instr reads 1KB contiguous) ----
  // A: pass p (0..7): row = (tid>>4) + p*16, col = (tid&15)*4 fp32
  const int ar = tid >> 4, acol = (tid & 15) * 4;
  const float* gA = A + (size_t)(rowblk + ar) * lda + k0 + acol;
  const int awb = (ar << 7) + (((((tid & 15) >> 1) ^ (ar & 7)) << 4)) + (tid & 1) * 8;
  // B: pass p (0..3): row = (tid>>3) + p*32, 16B chunk = tid&7
  const int br = tid >> 3, bc = tid & 7;
  const u16* gB = Bt + (size_t)br * ldb + k0 + bc * 8;
  const int bwb = (br << 7) + (((bc ^ (br & 7)) << 4));

  // ---- compute roles ----
  const int l = tid & 63, w = tid >> 6;
  const int wr = (w >> 1) * 64, wc = (w & 1) * 64;
  const int lrow = l & 15, lks = l >> 4, lsw = l & 7;

  f32x4 acc[4][4];
  #pragma unroll
  for (int mi = 0; mi < 4; ++mi)
    #pragma unroll
    for (int ni = 0; ni < 4; ++ni) acc[mi][ni] = (f32x4){0.f, 0.f, 0.f, 0.f};

  f32x4 ra[8]; u16x8 rbv[4];

#define LOADG(S)                                                              \
  {                                                                           \
    const float* pA = gA + (size_t)(S) * 64;                                  \
    const u16*   pB = gB + (size_t)(S) * 64;                                  \
    _Pragma("unroll")                                                         \
    for (int p = 0; p < 8; ++p) ra[p] = *reinterpret_cast<const f32x4*>(pA + (size_t)p * 16 * lda); \
    _Pragma("unroll")                                                         \
    for (int p = 0; p < 4; ++p) rbv[p] = *reinterpret_cast<const u16x8*>(pB + (size_t)p * 32 * ldb); \
  }

#define STORE_LDS()                                                           \
  {                                                                           \
    _Pragma("unroll")                                                         \
    for (int p = 0; p < 8; ++p) {                                             \
      f16x4 h;                                                                \
      h[0] = (_Float16)ra[p][0]; h[1] = (_Float16)ra[p][1];                   \
      h[2] = (_Float16)ra[p][2]; h[3] = (_Float16)ra[p][3];                   \
      *reinterpret_cast<f16x4*>(smem + LDS_A + awb + p * (16 << 7)) = h;      \
    }                                                                         \
    _Pragma("unroll")                                                         \
    for (int p = 0; p < 4; ++p)                                               \
      *reinterpret_cast<u16x8*>(smem + LDS_B + bwb + p * (32 << 7)) = rbv[p]; \
  }

  if (nsteps > 0) { LOADG(0); STORE_LDS(); }
  __syncthreads();

  for (int s = 0; s < nsteps; ++s) {
    if (s + 1 < nsteps) LOADG(s + 1);            // prefetch next tile to regs
    #pragma unroll
    for (int ks = 0; ks < 2; ++ks) {
      const int fo = ((((ks << 2) | lks) ^ lsw) << 4);
      f16x8 bf[4];
      #pragma unroll
      for (int ni = 0; ni < 4; ++ni)
        bf[ni] = *reinterpret_cast<const f16x8*>(
            smem + LDS_B + ((wc + ni * 16 + lrow) << 7) + fo);
      #pragma unroll
      for (int mi = 0; mi < 4; ++mi) {
        f16x8 af = *reinterpret_cast<const f16x8*>(
            smem + LDS_A + ((wr + mi * 16 + lrow) << 7) + fo);
        #pragma unroll
        for (int ni = 0; ni < 4; ++ni)
          acc[mi][ni] = __builtin_amdgcn_mfma_f32_16x16x32_f16(af, bf[ni], acc[mi][ni], 0, 0, 0);
      }
    }
    __syncthreads();
    if (s + 1 < nsteps) STORE_LDS();
    __syncthreads();
  }

  // epilogue: partial store (C/D: col = lane&15, row = (lane>>4)*4 + reg)
  float* o = part + (size_t)blockIdx.y * n * 128;
  #pragma unroll
  for (int mi = 0; mi < 4; ++mi)
    #pragma unroll
    for (int ni = 0; ni < 4; ++ni) {
      const int gr = rowblk + wr + mi * 16 + lks * 4;
      const int gc = wc + ni * 16 + lrow;
      f32x4 v = acc[mi][ni];
      #pragma unroll
      for (int q = 0; q < 4; ++q) o[(size_t)(gr + q) * 128 + gc] = v[q];
    }
#undef LOADG
#undef STORE_LDS
}

// ---------------- split-K reduce + epilogues ----------------
__global__ void reduce_sigmoid_k(const float* __restrict__ part, int S, size_t stride,
                                 const float* __restrict__ inv, float* __restrict__ out, int n) {
  int i = blockIdx.x * blockDim.x + threadIdx.x;
  if (i >= n * 32) return;
  size_t off = (size_t)i * 4;
  float4 s = *reinterpret_cast<const float4*>(part + off);
  for (int sp = 1; sp < S; ++sp) {
    float4 v = *reinterpret_cast<const float4*>(part + (size_t)sp * stride + off);
    s.x += v.x; s.y += v.y; s.z += v.z; s.w += v.w;
  }
  float iv = inv[off >> 7];
  s.x = 1.f / (1.f + expf(-iv * s.x));
  s.y = 1.f / (1.f + expf(-iv * s.y));
  s.z = 1.f / (1.f + expf(-iv * s.z));
  s.w = 1.f / (1.f + expf(-iv * s.w));
  *reinterpret_cast<float4*>(out + off) = s;
}

__global__ void reduce_add_k(const float* __restrict__ part, int S, size_t stride,
                             const float* __restrict__ h, float* __restrict__ z, int n) {
  int i = blockIdx.x * blockDim.x + threadIdx.x;
  if (i >= n * 32) return;
  size_t off = (size_t)i * 4;
  float4 s = *reinterpret_cast<const float4*>(part + off);
  for (int sp = 1; sp < S; ++sp) {
    float4 v = *reinterpret_cast<const float4*>(part + (size_t)sp * stride + off);
    s.x += v.x; s.y += v.y; s.z += v.z; s.w += v.w;
  }
  float4 hv = *reinterpret_cast<const float4*>(h + off);
  s.x += hv.x; s.y += hv.y; s.z += hv.z; s.w += hv.w;
  *reinterpret_cast<float4*>(z + off) = s;
}

// ---------------- graph norm ----------------
__device__ inline int lbound(const int* __restrict__ b, int n, int v) {
  int lo = 0, hi = n;
  while (lo < hi) { int mid = (lo + hi) >> 1; if (b[mid] < v) lo = mid + 1; else hi = mid; }
  return lo;
}

__global__ void gn_stats_k(const float* __restrict__ z, const int* __restrict__ batch, int n,
                           const float* __restrict__ mss,
                           float* __restrict__ meanms, float* __restrict__ rstd) {
  const int g = blockIdx.x;
  const int c = threadIdx.x;
  __shared__ int lohi[2];
  if (c == 0) { lohi[0] = lbound(batch, n, g); lohi[1] = lbound(batch, n, g + 1); }
  __syncthreads();
  const int lo = lohi[0], hi = lohi[1];
  const float cnt = (float)max(hi - lo, 1);
  float sum = 0.f;
  for (int r = lo; r < hi; ++r) sum += z[(size_t)r * 128 + c];
  const float mn = (sum / cnt) * mss[c];
  float m2 = 0.f;
  for (int r = lo; r < hi; ++r) { float o = z[(size_t)r * 128 + c] - mn; m2 += o * o; }
  meanms[g * 128 + c] = mn;
  rstd[g * 128 + c] = rsqrtf(m2 / cnt + EPSV);
}

__global__ void gn_apply_k(const float* __restrict__ z, const int* __restrict__ batch,
                           const float* __restrict__ w, const float* __restrict__ b,
                           const float* __restrict__ meanms, const float* __restrict__ rstd,
                           float* __restrict__ out, int n) {
  int i = blockIdx.x * blockDim.x + threadIdx.x;
  if (i >= n * 32) return;
  const int r = i >> 5;
  const int c = (i & 31) * 4;
  const int g = batch[r];
  float4 zv = *reinterpret_cast<const float4*>(z + (size_t)r * 128 + c);
  float4 mm = *reinterpret_cast<const float4*>(meanms + g * 128 + c);
  float4 rs = *reinterpret_cast<const float4*>(rstd + g * 128 + c);
  float4 wv = *reinterpret_cast<const float4*>(w + c);
  float4 bv = *reinterpret_cast<const float4*>(b + c);
  float4 o;
  o.x = wv.x * (zv.x - mm.x) * rs.x + bv.x;
  o.y = wv.y * (zv.y - mm.y) * rs.y + bv.y;
  o.z = wv.z * (zv.z - mm.z) * rs.z + bv.z;
  o.w = wv.w * (zv.w - mm.w) * rs.w + bv.w;
  *reinterpret_cast<float4*>(out + (size_t)r * 128 + c) = o;
}

// ---------------------------------------------------------------------------
extern "C" void kernel_launch(void* const* d_in, const int* in_sizes, int n_in,
                              void* d_out, int out_size, void* d_ws, size_t ws_size,
                              hipStream_t stream) {
  const float* x0   = (const float*)d_in[0];
  const float* x1   = (const float*)d_in[1];
  const float* x2   = (const float*)d_in[2];
  const float* L0   = (const float*)d_in[3];
  const float* L1   = (const float*)d_in[4];
  const float* L2   = (const float*)d_in[5];
  const float* inc1 = (const float*)d_in[6];
  const float* inc2 = (const float*)d_in[7];
  const float* W0   = (const float*)d_in[8];
  const float* W1   = (const float*)d_in[9];
  const float* W2   = (const float*)d_in[10];
  const float* Wc1  = (const float*)d_in[11];
  const float* Wc2  = (const float*)d_in[12];
  const float* g1w  = (const float*)d_in[13];
  const float* g1b  = (const float*)d_in[14];
  const float* g1m  = (const float*)d_in[15];
  const float* g2w  = (const float*)d_in[16];
  const float* g2b  = (const float*)d_in[17];
  const float* g2m  = (const float*)d_in[18];
  const int*   bat0 = (const int*)d_in[19];
  const int*   bat1 = (const int*)d_in[20];

  const int N0 = 4096, N1 = 8192, N2 = 6144;

  float* ws = (float*)d_ws;
  size_t off = 0;
  auto alloc = [&](size_t nf) { float* p = ws + off; off += (nf + 63) & ~(size_t)63; return p; };
  float* inv0   = alloc(N0);
  float* inv1   = alloc(N1);
  float* inv2   = alloc(N2);
  u16*   tT     = (u16*)alloc((size_t)N1 * 64);    // fp16 transposed t: [128][<=N1]
  float* h0     = alloc((size_t)N0 * 128);
  float* h1     = alloc((size_t)N1 * 128);
  float* z      = alloc((size_t)N1 * 128);
  float* meanms = alloc(64 * 128);
  float* rstd   = alloc(64 * 128);
  float* part   = alloc((size_t)49152 * 128);      // split-K partials (all launches: S*n = 49152)

  float* out0 = (float*)d_out;
  float* out1 = out0 + (size_t)N0 * 128;
  float* out2 = out1 + (size_t)N1 * 128;

  rowsum_inv_k<<<N0, 256, 0, stream>>>(L0, inv0, N0);
  rowsum_inv_k<<<N1, 256, 0, stream>>>(L1, inv1, N1);
  rowsum_inv_k<<<N2, 256, 0, stream>>>(L2, inv2, N2);

  // --- h2 -> out2 ---  (48 x S=8 = 384 blocks, kchunk 768)
  gemm_small_k<1><<<N2 / 64, 256, 0, stream>>>(x2, W2, tT, N2, inv2);
  mfma_gemm_k<<<dim3(N2 / 128, 8), 256, 0, stream>>>(L2, N2, tT, N2, part, N2, N2, 768);
  reduce_sigmoid_k<<<N2 * 32 / 256, 256, 0, stream>>>(part, 8, (size_t)N2 * 128, inv2, out2, N2);

  // --- h1 ---  (64 x S=6 = 384 blocks, kchunk 1408; last split 1152)
  gemm_small_k<1><<<N1 / 64, 256, 0, stream>>>(x1, W1, tT, N1, inv1);
  mfma_gemm_k<<<dim3(N1 / 128, 6), 256, 0, stream>>>(L1, N1, tT, N1, part, N1, N1, 1408);
  reduce_sigmoid_k<<<N1 * 32 / 256, 256, 0, stream>>>(part, 6, (size_t)N1 * 128, inv1, h1, N1);

  // --- h0 ---  (32 x S=12 = 384 blocks, kchunk 384; split 11 empty -> zeros)
  gemm_small_k<1><<<N0 / 64, 256, 0, stream>>>(x0, W0, tT, N0, inv0);
  mfma_gemm_k<<<dim3(N0 / 128, 12), 256, 0, stream>>>(L0, N0, tT, N0, part, N0, N0, 384);
  reduce_sigmoid_k<<<N0 * 32 / 256, 256, 0, stream>>>(part, 12, (size_t)N0 * 128, inv0, h0, N0);

  // --- x1_out ---  (64 x S=6 = 384 blocks, K = N2, kchunk 1024)
  gemm_small_k<2><<<N2 / 64, 256, 0, stream>>>(out2, Wc1, tT, N2, nullptr);
  mfma_gemm_k<<<dim3(N1 / 128, 6), 256, 0, stream>>>(inc2, N2, tT, N2, part, N1, N2, 1024);
  reduce_add_k<<<N1 * 32 / 256, 256, 0, stream>>>(part, 6, (size_t)N1 * 128, h1, z, N1);
  gn_stats_k<<<64, 128, 0, stream>>>(z, bat1, N1, g1m, meanms, rstd);
  gn_apply_k<<<N1 * 32 / 256, 256, 0, stream>>>(z, bat1, g1w, g1b, meanms, rstd, out1, N1);

  // --- x0_out ---  (32 x S=12 = 384 blocks, K = N1, kchunk 704)
  gemm_small_k<2><<<N1 / 64, 256, 0, stream>>>(out1, Wc2, tT, N1, nullptr);
  mfma_gemm_k<<<dim3(N0 / 128, 12), 256, 0, stream>>>(inc1, N1, tT, N1, part, N0, N1, 704);
  reduce_add_k<<<N0 * 32 / 256, 256, 0, stream>>>(part, 12, (size_t)N0 * 128, h0, z, N0);
  gn_stats_k<<<64, 128, 0, stream>>>(z, bat0, N0, g2m, meanms, rstd);
  gn_apply_k<<<N0 * 32 / 256, 256, 0, stream>>>(z, bat0, g2w, g2b, meanms, rstd, out0, N0);
}